// Round 4
// baseline (59.958 us; speedup 1.0000x reference)
//
#include <hip/hip_runtime.h>
#include <math.h>

#define EPSF 1e-6f
#define NB 4
#define NR 16384
#define NS 48
#define NSEG 47
#define NRAYS (NB * NR)
#define KL 8                  // lanes per ray
#define SPL 6                 // samples per lane
#define RPT 8                 // rays per tile == rays per wave
#define TPB 64                // single-wave blocks: no s_barrier anywhere
#define NTILES (NRAYS / RPT)  // 8192
#define NBLK (NTILES / 2)     // 4096 blocks, 2 tiles each (double-buffered)

// LDS buffer (floats): colors 8*144=1152 | semantics 8*192=1536 -> 2688/buffer
#define BC 0
#define BS 1152
#define BUFF 2688
#define LTOT (2 * BUFF + 16)  // +pad for guarded-unused tail reads
// regions reused inside the CONSUMED buffer (reads precede these writes):
#define PW 0    // weights: 8*47 = 376 floats (linear image of global layout)
#define PP 384  // partials: [8 rays][8 lanes][9-pad] = 576 floats

typedef const __attribute__((address_space(1))) void as1_cvoid;
typedef __attribute__((address_space(3))) void as3_void;

__device__ __forceinline__ unsigned int f2ord(float f) {
    unsigned int u = __float_as_uint(f);
    return (u & 0x80000000u) ? ~u : (u | 0x80000000u);
}
__device__ __forceinline__ float ord2f(unsigned int v) {
    return __uint_as_float((v & 0x80000000u) ? (v ^ 0x80000000u) : ~v);
}
// fast softplus: max(x,0) + log(1+exp(-|x|)) with native exp/log (abs err ~1e-7)
__device__ __forceinline__ float softplus_f(float x) {
    return fmaxf(x, 0.0f) + __logf(1.0f + __expf(-fabsf(x)));
}

// depths are sorted along the sample axis (jnp.sort in setup_inputs), so the
// global min/max are min over rays of d[ray][0] and max of d[ray][47].
__global__ __launch_bounds__(256) void minmax_ends(const float* __restrict__ z,
                                                   unsigned int* mm) {
    const int ray = blockIdx.x * 256 + threadIdx.x;  // grid covers all rays
    float lmin = z[(size_t)ray * NS];
    float lmax = z[(size_t)ray * NS + (NS - 1)];
#pragma unroll
    for (int off = 32; off > 0; off >>= 1) {
        lmin = fminf(lmin, __shfl_down(lmin, off));
        lmax = fmaxf(lmax, __shfl_down(lmax, off));
    }
    if ((threadIdx.x & 63) == 0) {
        atomicMin(&mm[0], f2ord(lmin));
        atomicMax(&mm[1], f2ord(lmax));
    }
}

// coalesced global->LDS DMA of one tile's colors (4608B) + semantics (6144B):
// exactly 11 vmem instructions per wave, LDS dest is wave-uniform + lane*16.
__device__ __forceinline__ void stage_cs(const float* __restrict__ colors,
                                         const float* __restrict__ semantics,
                                         int ray0, float* buf, int lane) {
    const float* c = colors + (size_t)ray0 * 144;
    const float* s = semantics + (size_t)ray0 * 192;
#pragma unroll
    for (int i = 0; i < 4; ++i)
        __builtin_amdgcn_global_load_lds((as1_cvoid*)(c + i * 256 + lane * 4),
                                         (as3_void*)(buf + BC + i * 256), 16, 0, 0);
    if (lane < 32)
        __builtin_amdgcn_global_load_lds((as1_cvoid*)(c + 1024 + lane * 4),
                                         (as3_void*)(buf + BC + 1024), 16, 0, 0);
#pragma unroll
    for (int i = 0; i < 6; ++i)
        __builtin_amdgcn_global_load_lds((as1_cvoid*)(s + i * 256 + lane * 4),
                                         (as3_void*)(buf + BS + i * 256), 16, 0, 0);
}

// densities+depths prefetch straight to registers (small, ~24 lines/instr)
__device__ __forceinline__ void load_dz(const float* __restrict__ densities,
                                        const float* __restrict__ depths,
                                        int ray0, int lane, float2& d0, float2& d1,
                                        float2& d2, float2& z0, float2& z1,
                                        float2& z2) {
    const int r = lane >> 3, t = lane & 7;
    const float2* dp = (const float2*)(densities + (size_t)(ray0 + r) * NS) + t * 3;
    const float2* zp = (const float2*)(depths + (size_t)(ray0 + r) * NS) + t * 3;
    d0 = dp[0]; d1 = dp[1]; d2 = dp[2];
    z0 = zp[0]; z1 = zp[1]; z2 = zp[2];
}

__device__ __forceinline__ void tile_body(float* lds, int cb, int ray0, int lv,
                                          float2 dd0, float2 dd1, float2 dd2,
                                          float2 zz0, float2 zz1, float2 zz2,
                                          float dmin, float dmax,
                                          float* __restrict__ out, int lane) {
    const int r = lane >> 3, t = lane & 7;

    float C0[7], C1[7], C2[7], DN[7], Z[7], S0[7], S1[7], S2[7], S3[7];
    {
        const float* p0 = lds + cb + BC + r * 144 + 18 * t;  // 8B aligned
        const float2* p = (const float2*)p0;
        float2 q0 = p[0], q1 = p[1], q2 = p[2], q3 = p[3], q4 = p[4];
        float2 q5 = p[5], q6 = p[6], q7 = p[7], q8 = p[8], q9 = p[9];
        float qa = p0[20];
        C0[0] = q0.x; C1[0] = q0.y; C2[0] = q1.x;
        C0[1] = q1.y; C1[1] = q2.x; C2[1] = q2.y;
        C0[2] = q3.x; C1[2] = q3.y; C2[2] = q4.x;
        C0[3] = q4.y; C1[3] = q5.x; C2[3] = q5.y;
        C0[4] = q6.x; C1[4] = q6.y; C2[4] = q7.x;
        C0[5] = q7.y; C1[5] = q8.x; C2[5] = q8.y;
        C0[6] = q9.x; C1[6] = q9.y; C2[6] = qa;
    }
    {
        const float4* p = (const float4*)(lds + cb + BS + r * 192 + 24 * t);
#pragma unroll
        for (int j = 0; j < 7; ++j) {
            float4 u = p[j];
            S0[j] = u.x; S1[j] = u.y; S2[j] = u.z; S3[j] = u.w;
        }
    }
    DN[0] = dd0.x; DN[1] = dd0.y; DN[2] = dd1.x;
    DN[3] = dd1.y; DN[4] = dd2.x; DN[5] = dd2.y;
    Z[0] = zz0.x; Z[1] = zz0.y; Z[2] = zz1.x;
    Z[3] = zz1.y; Z[4] = zz2.x; Z[5] = zz2.y;
    DN[6] = __shfl_down(DN[0], 1, KL);  // boundary sample (t==7 guarded-unused)
    Z[6] = __shfl_down(Z[0], 1, KL);

    float T = 1.0f;
    float wl[SPL];
    float acc_r = 0.f, acc_g = 0.f, acc_b = 0.f, acc_d = 0.f;
    float acc_s0 = 0.f, acc_s1 = 0.f, acc_s2 = 0.f, acc_s3 = 0.f;

#pragma unroll
    for (int j = 0; j < SPL; ++j) {
        wl[j] = 0.0f;
        if (j < 5 || t < 7) {  // lane 7 only has 5 segments
            float delta = Z[j + 1] - Z[j];
            float cm0 = (C0[j] + C0[j + 1]) * 0.5f;
            float cm1 = (C1[j] + C1[j + 1]) * 0.5f;
            float cm2 = (C2[j] + C2[j + 1]) * 0.5f;
            float dnm = (DN[j] + DN[j + 1]) * 0.5f;
            float zm = (Z[j] + Z[j + 1]) * 0.5f;
            float sm0 = (S0[j] + S0[j + 1]) * 0.5f;
            float sm1 = (S1[j] + S1[j + 1]) * 0.5f;
            float sm2 = (S2[j] + S2[j + 1]) * 0.5f;
            float sm3 = (S3[j] + S3[j + 1]) * 0.5f;

            float sp_ = softplus_f(dnm);
            float alpha = 1.0f - __expf(-sp_ * delta);

            float factor, o0, o1, o2, o3;
            if (lv == 1) {
                factor = 1.0f - sm0;
                float inv = 1.0f / (sm1 + sm2 + sm3 + EPSF);
                o0 = 0.0f;
                o1 = (sm1 + EPSF) * inv;
                o2 = (sm2 + EPSF) * inv;
                o3 = (sm3 + EPSF) * inv;
            } else if (lv == 2) {
                factor = 1.0f - sm0 - sm3;
                float inv = 1.0f / (sm1 + sm2 + EPSF);
                o0 = 0.0f;
                o1 = (sm1 + EPSF) * inv;
                o2 = (sm2 + EPSF) * inv;
                o3 = 0.0f;
            } else {
                factor = 1.0f;
                o0 = sm0; o1 = sm1; o2 = sm2; o3 = sm3;
            }

            alpha *= factor;
            float w = alpha * T;
            T *= (1.0f - alpha + 1e-10f);
            wl[j] = w;

            acc_r += w * cm0;
            acc_g += w * cm1;
            acc_b += w * cm2;
            acc_d += w * zm;
            acc_s0 += w * o0;
            acc_s1 += w * o1;
            acc_s2 += w * o2;
            acc_s3 += w * o3;
        }
    }

    // inclusive product scan of local transmittance across the 8 lanes
    float p = T;
#pragma unroll
    for (int off = 1; off < KL; off <<= 1) {
        float u = __shfl_up(p, off, KL);
        if (t >= off) p *= u;
    }
    float Tstart = __shfl_up(p, 1, KL);
    if (t == 0) Tstart = 1.0f;

    acc_r *= Tstart; acc_g *= Tstart; acc_b *= Tstart; acc_d *= Tstart;
    acc_s0 *= Tstart; acc_s1 *= Tstart; acc_s2 *= Tstart; acc_s3 *= Tstart;

    // weights -> consumed LDS buffer (linear image of global layout)
#pragma unroll
    for (int j = 0; j < SPL; ++j) {
        if (j < 5 || t < 7)
            lds[cb + PW + r * NSEG + t * SPL + j] = wl[j] * Tstart;
    }

    // per-lane partial composites -> LDS (replaces 24-deep shuffle chain)
    {
        const int pb = cb + PP + r * 72 + t * 9;
        lds[pb + 0] = acc_r;  lds[pb + 1] = acc_g;
        lds[pb + 2] = acc_b;  lds[pb + 3] = acc_d;
        lds[pb + 4] = acc_s0; lds[pb + 5] = acc_s1;
        lds[pb + 6] = acc_s2; lds[pb + 7] = acc_s3;
    }

    // transposed re-read: lane <-> (ray rr, quantity qq); 8 independent adds
    {
        const int rr = lane >> 3, qq = lane & 7;
        const int qb = cb + PP + rr * 72 + qq;
        float v = lds[qb] + lds[qb + 9];
        v += lds[qb + 18]; v += lds[qb + 27];
        v += lds[qb + 36]; v += lds[qb + 45];
        v += lds[qb + 54]; v += lds[qb + 63];

        const int ray = ray0 + rr;
        size_t oidx;
        if (qq < 3) {
            oidx = (size_t)ray * 3 + qq;
        } else if (qq == 3) {
            if (isnan(v)) v = INFINITY;
            v = fminf(fmaxf(v, dmin), dmax);
            oidx = (size_t)NRAYS * 3 + ray;
        } else {
            oidx = (size_t)NRAYS * 4 + (size_t)ray * 4 + (qq - 4);
        }
        out[oidx] = v;  // 1 store
    }

    // coalesced float4 copy-out of the tile's 376 weight floats (2 stores)
    {
        const float4* src = (const float4*)(lds + cb + PW);
        float4* dst = (float4*)(out + (size_t)NRAYS * 8 + (size_t)ray0 * NSEG);
        dst[lane] = src[lane];
        if (lane < 94 - 64) dst[lane + 64] = src[lane + 64];
    }
}

__global__ __launch_bounds__(TPB) void march_kernel(
    const float* __restrict__ colors, const float* __restrict__ densities,
    const float* __restrict__ depths, const float* __restrict__ semantics,
    const int* __restrict__ levels, const unsigned int* __restrict__ mm,
    float* __restrict__ out) {
    __shared__ float lds[LTOT];
    const int lane = threadIdx.x;
    const int ray0a = blockIdx.x * (2 * RPT);
    const int ray0b = ray0a + RPT;

    // uniform scalar loads, pinned before the fences
    const float dmin = ord2f(mm[0]);
    const float dmax = ord2f(mm[1]);
    const int lvA = levels[ray0a >> 14];
    const int lvB = levels[ray0b >> 14];

    // ---- pipelined prologue: both tiles' loads in flight ----
    stage_cs(colors, semantics, ray0a, lds, lane);
    float2 ad0, ad1, ad2, az0, az1, az2;
    load_dz(densities, depths, ray0a, lane, ad0, ad1, ad2, az0, az1, az2);
    stage_cs(colors, semantics, ray0b, lds + BUFF, lane);
    float2 bd0, bd1, bd2, bz0, bz1, bz2;
    load_dz(densities, depths, ray0b, lane, bd0, bd1, bd2, bz0, bz1, bz2);

    // tile-b stage (11 DMA) + its 4-6 reg loads may stay outstanding (<=17);
    // everything older (tile-a DMA + reg loads) is drained.
    asm volatile("s_waitcnt vmcnt(17)" ::: "memory");
    tile_body(lds, 0, ray0a, lvA, ad0, ad1, ad2, az0, az1, az2, dmin, dmax, out,
              lane);

    // only tile-a's 3 output stores may stay outstanding; tile-b DMA drained.
    asm volatile("s_waitcnt vmcnt(3)" ::: "memory");
    tile_body(lds, BUFF, ray0b, lvB, bd0, bd1, bd2, bz0, bz1, bz2, dmin, dmax,
              out, lane);
}

extern "C" void kernel_launch(void* const* d_in, const int* in_sizes, int n_in,
                              void* d_out, int out_size, void* d_ws, size_t ws_size,
                              hipStream_t stream) {
    const float* colors = (const float*)d_in[0];
    const float* densities = (const float*)d_in[1];
    const float* depths = (const float*)d_in[2];
    const float* semantics = (const float*)d_in[3];
    const int* levels = (const int*)d_in[4];
    float* out = (float*)d_out;
    unsigned int* mm = (unsigned int*)d_ws;

    hipMemsetAsync(mm, 0xFF, 4, stream);                 // min ordinal = UINT_MAX
    hipMemsetAsync((void*)(mm + 1), 0x00, 4, stream);    // max ordinal = 0
    minmax_ends<<<NRAYS / 256, 256, 0, stream>>>(depths, mm);
    march_kernel<<<NBLK, TPB, 0, stream>>>(colors, densities, depths, semantics,
                                           levels, mm, out);
}

// Round 5
// 58.175 us; speedup vs baseline: 1.0307x; 1.0307x over previous
//
#include <hip/hip_runtime.h>
#include <math.h>

#define EPSF 1e-6f
#define NB 4
#define NR 16384
#define NS 48
#define NSEG 47
#define NRAYS (NB * NR)
#define KL 8    // lanes per ray
#define SPL 6   // samples per lane

__device__ __forceinline__ unsigned int f2ord(float f) {
    unsigned int u = __float_as_uint(f);
    return (u & 0x80000000u) ? ~u : (u | 0x80000000u);
}
__device__ __forceinline__ float ord2f(unsigned int v) {
    return __uint_as_float((v & 0x80000000u) ? (v ^ 0x80000000u) : ~v);
}
// fast softplus: max(x,0) + log(1+exp(-|x|)) with native exp/log
__device__ __forceinline__ float softplus_f(float x) {
    return fmaxf(x, 0.0f) + __logf(1.0f + __expf(-fabsf(x)));
}

// depths are sorted along the sample axis (jnp.sort in setup_inputs), so the
// global min/max are min over rays of d[ray][0] and max of d[ray][47].
__global__ __launch_bounds__(256) void minmax_ends(const float* __restrict__ z,
                                                   unsigned int* mm) {
    const int ray = blockIdx.x * 256 + threadIdx.x;
    float lmin = z[(size_t)ray * NS];
    float lmax = z[(size_t)ray * NS + (NS - 1)];
#pragma unroll
    for (int off = 32; off > 0; off >>= 1) {
        lmin = fminf(lmin, __shfl_down(lmin, off));
        lmax = fmaxf(lmax, __shfl_down(lmax, off));
    }
    if ((threadIdx.x & 63) == 0) {
        atomicMin(&mm[0], f2ord(lmin));
        atomicMax(&mm[1], f2ord(lmax));
    }
}

__global__ __launch_bounds__(256, 4) void march_kernel(
    const float* __restrict__ colors, const float* __restrict__ densities,
    const float* __restrict__ depths, const float* __restrict__ semantics,
    const int* __restrict__ levels, const unsigned int* __restrict__ mm,
    float* __restrict__ out) {
    const int gtid = blockIdx.x * 256 + threadIdx.x;
    const int ray = gtid >> 3;   // 8 lanes per ray
    const int t = gtid & 7;      // owns samples 6t..6t+5 (+ boundary 6t+6)
    const int lv = levels[ray >> 14];

    // per-lane chunk bases: byte offsets are 72*gtid / 96*gtid / 24*gtid —
    // block-contiguous per lane, minimal cache-line footprint per wave.
    const float* cbase = colors + (size_t)ray * 144 + t * 18;
    const float4* sbase = (const float4*)(semantics + (size_t)ray * 192 + t * 24);
    const float* dbase = densities + (size_t)ray * 48 + t * 6;
    const float* zbase = depths + (size_t)ray * 48 + t * 6;

    // lane 7 has no boundary sample; clamp its tail loads in-bounds (unused)
    const int c_t2 = (t < 7) ? 18 : 0;
    const int c_t1 = (t < 7) ? 20 : 0;
    const int s_t = (t < 7) ? 6 : 0;
    const int dz_t = (t < 7) ? 6 : 0;

    // ---- issue ALL loads up front (26 independent vmem ops) ----
    const float2* cp = (const float2*)cbase;
    float2 q0 = cp[0], q1 = cp[1], q2 = cp[2], q3 = cp[3], q4 = cp[4];
    float2 q5 = cp[5], q6 = cp[6], q7 = cp[7], q8 = cp[8];
    float2 q9 = *(const float2*)(cbase + c_t2);
    float qa = cbase[c_t1];

    float4 u0 = sbase[0], u1 = sbase[1], u2 = sbase[2], u3 = sbase[3];
    float4 u4 = sbase[4], u5 = sbase[5], u6 = sbase[s_t];

    const float2* dp = (const float2*)dbase;
    float2 r0 = dp[0], r1 = dp[1], r2 = dp[2];
    float r3 = dbase[dz_t];
    const float2* zp = (const float2*)zbase;
    float2 e0 = zp[0], e1 = zp[1], e2 = zp[2];
    float e3 = zbase[dz_t];

    float C0[7], C1[7], C2[7], DN[7], Z[7], S0[7], S1[7], S2[7], S3[7];
    C0[0] = q0.x; C1[0] = q0.y; C2[0] = q1.x;
    C0[1] = q1.y; C1[1] = q2.x; C2[1] = q2.y;
    C0[2] = q3.x; C1[2] = q3.y; C2[2] = q4.x;
    C0[3] = q4.y; C1[3] = q5.x; C2[3] = q5.y;
    C0[4] = q6.x; C1[4] = q6.y; C2[4] = q7.x;
    C0[5] = q7.y; C1[5] = q8.x; C2[5] = q8.y;
    C0[6] = q9.x; C1[6] = q9.y; C2[6] = qa;
    S0[0] = u0.x; S1[0] = u0.y; S2[0] = u0.z; S3[0] = u0.w;
    S0[1] = u1.x; S1[1] = u1.y; S2[1] = u1.z; S3[1] = u1.w;
    S0[2] = u2.x; S1[2] = u2.y; S2[2] = u2.z; S3[2] = u2.w;
    S0[3] = u3.x; S1[3] = u3.y; S2[3] = u3.z; S3[3] = u3.w;
    S0[4] = u4.x; S1[4] = u4.y; S2[4] = u4.z; S3[4] = u4.w;
    S0[5] = u5.x; S1[5] = u5.y; S2[5] = u5.z; S3[5] = u5.w;
    S0[6] = u6.x; S1[6] = u6.y; S2[6] = u6.z; S3[6] = u6.w;
    DN[0] = r0.x; DN[1] = r0.y; DN[2] = r1.x;
    DN[3] = r1.y; DN[4] = r2.x; DN[5] = r2.y; DN[6] = r3;
    Z[0] = e0.x; Z[1] = e0.y; Z[2] = e1.x;
    Z[3] = e1.y; Z[4] = e2.x; Z[5] = e2.y; Z[6] = e3;

    // ---- local pass: T starts at 1 within this lane's chunk ----
    float T = 1.0f;
    float wl[SPL];
    float acc_r = 0.f, acc_g = 0.f, acc_b = 0.f, acc_d = 0.f;
    float acc_s0 = 0.f, acc_s1 = 0.f, acc_s2 = 0.f, acc_s3 = 0.f;

#pragma unroll
    for (int j = 0; j < SPL; ++j) {
        wl[j] = 0.0f;
        if (j < 5 || t < 7) {  // lane 7 only has 5 segments
            float delta = Z[j + 1] - Z[j];
            float cm0 = (C0[j] + C0[j + 1]) * 0.5f;
            float cm1 = (C1[j] + C1[j + 1]) * 0.5f;
            float cm2 = (C2[j] + C2[j + 1]) * 0.5f;
            float dnm = (DN[j] + DN[j + 1]) * 0.5f;
            float zm = (Z[j] + Z[j + 1]) * 0.5f;
            float sm0 = (S0[j] + S0[j + 1]) * 0.5f;
            float sm1 = (S1[j] + S1[j + 1]) * 0.5f;
            float sm2 = (S2[j] + S2[j + 1]) * 0.5f;
            float sm3 = (S3[j] + S3[j + 1]) * 0.5f;

            float sp_ = softplus_f(dnm);
            float alpha = 1.0f - __expf(-sp_ * delta);

            float factor, o0, o1, o2, o3;
            if (lv == 1) {
                factor = 1.0f - sm0;
                float inv = 1.0f / (sm1 + sm2 + sm3 + EPSF);
                o0 = 0.0f;
                o1 = (sm1 + EPSF) * inv;
                o2 = (sm2 + EPSF) * inv;
                o3 = (sm3 + EPSF) * inv;
            } else if (lv == 2) {
                factor = 1.0f - sm0 - sm3;
                float inv = 1.0f / (sm1 + sm2 + EPSF);
                o0 = 0.0f;
                o1 = (sm1 + EPSF) * inv;
                o2 = (sm2 + EPSF) * inv;
                o3 = 0.0f;
            } else {
                factor = 1.0f;
                o0 = sm0; o1 = sm1; o2 = sm2; o3 = sm3;
            }

            alpha *= factor;
            float w = alpha * T;
            T *= (1.0f - alpha + 1e-10f);
            wl[j] = w;

            acc_r += w * cm0;
            acc_g += w * cm1;
            acc_b += w * cm2;
            acc_d += w * zm;
            acc_s0 += w * o0;
            acc_s1 += w * o1;
            acc_s2 += w * o2;
            acc_s3 += w * o3;
        }
    }

    // ---- inclusive product scan of local transmittance across 8 lanes ----
    float p = T;
#pragma unroll
    for (int off = 1; off < KL; off <<= 1) {
        float u = __shfl_up(p, off, KL);
        if (t >= off) p *= u;
    }
    float Tstart = __shfl_up(p, 1, KL);
    if (t == 0) Tstart = 1.0f;

    acc_r *= Tstart; acc_g *= Tstart; acc_b *= Tstart; acc_d *= Tstart;
    acc_s0 *= Tstart; acc_s1 *= Tstart; acc_s2 *= Tstart; acc_s3 *= Tstart;

    // weights out (lane-contiguous 24B blocks; fire-and-forget stores)
    float* wbase = out + (size_t)NRAYS * 8 + (size_t)ray * NSEG + t * SPL;
#pragma unroll
    for (int j = 0; j < SPL; ++j) {
        if (j < 5 || t < 7) wbase[j] = wl[j] * Tstart;
    }

    // ---- reduce 8 partial composites across the group ----
#pragma unroll
    for (int off = KL / 2; off > 0; off >>= 1) {
        acc_r += __shfl_down(acc_r, off, KL);
        acc_g += __shfl_down(acc_g, off, KL);
        acc_b += __shfl_down(acc_b, off, KL);
        acc_d += __shfl_down(acc_d, off, KL);
        acc_s0 += __shfl_down(acc_s0, off, KL);
        acc_s1 += __shfl_down(acc_s1, off, KL);
        acc_s2 += __shfl_down(acc_s2, off, KL);
        acc_s3 += __shfl_down(acc_s3, off, KL);
    }

    if (t == 0) {
        const float dmin = ord2f(mm[0]);
        const float dmax = ord2f(mm[1]);
        if (isnan(acc_d)) acc_d = INFINITY;
        acc_d = fminf(fmaxf(acc_d, dmin), dmax);

        out[ray * 3 + 0] = acc_r;
        out[ray * 3 + 1] = acc_g;
        out[ray * 3 + 2] = acc_b;
        out[NRAYS * 3 + ray] = acc_d;
        out[NRAYS * 4 + ray * 4 + 0] = acc_s0;
        out[NRAYS * 4 + ray * 4 + 1] = acc_s1;
        out[NRAYS * 4 + ray * 4 + 2] = acc_s2;
        out[NRAYS * 4 + ray * 4 + 3] = acc_s3;
    }
}

extern "C" void kernel_launch(void* const* d_in, const int* in_sizes, int n_in,
                              void* d_out, int out_size, void* d_ws, size_t ws_size,
                              hipStream_t stream) {
    const float* colors = (const float*)d_in[0];
    const float* densities = (const float*)d_in[1];
    const float* depths = (const float*)d_in[2];
    const float* semantics = (const float*)d_in[3];
    const int* levels = (const int*)d_in[4];
    float* out = (float*)d_out;
    unsigned int* mm = (unsigned int*)d_ws;

    hipMemsetAsync(mm, 0xFF, 4, stream);               // min ordinal = UINT_MAX
    hipMemsetAsync((void*)(mm + 1), 0x00, 4, stream);  // max ordinal = 0
    minmax_ends<<<NRAYS / 256, 256, 0, stream>>>(depths, mm);
    march_kernel<<<(NRAYS * KL) / 256, 256, 0, stream>>>(
        colors, densities, depths, semantics, levels, mm, out);
}

// Round 6
// 56.374 us; speedup vs baseline: 1.0636x; 1.0319x over previous
//
#include <hip/hip_runtime.h>
#include <math.h>

#define EPSF 1e-6f
#define NB 4
#define NR 16384
#define NS 48
#define NSEG 47
#define NRAYS (NB * NR)
#define KL 8                 // lanes per ray
#define SPL 6                // samples per lane
#define RPT 8                // rays per tile == rays per wave == rays per block
#define TPB 64               // single-wave blocks: no s_barrier anywhere
#define NBLK (NRAYS / RPT)   // 8192 blocks

// LDS dword offsets (10880 B total -> 14 blocks/CU)
#define LC 0                 // colors, linear image: 8*144 = 1152
#define LSM 1152             // semantics, PADDED per-ray stride 196: 8*196 = 1568
#define LTOT 2720
#define LW LC                // weights staging reuses colors region (376 dwords)
#define LP LSM               // partials reuse semantics region (<=576 dwords)

typedef const __attribute__((address_space(1))) void as1_cvoid;
typedef __attribute__((address_space(3))) void as3_void;

__device__ __forceinline__ unsigned int f2ord(float f) {
    unsigned int u = __float_as_uint(f);
    return (u & 0x80000000u) ? ~u : (u | 0x80000000u);
}
__device__ __forceinline__ float ord2f(unsigned int v) {
    return __uint_as_float((v & 0x80000000u) ? (v ^ 0x80000000u) : ~v);
}
// fast softplus: max(x,0) + log(1+exp(-|x|)) with native exp/log
__device__ __forceinline__ float softplus_f(float x) {
    return fmaxf(x, 0.0f) + __logf(1.0f + __expf(-fabsf(x)));
}

// depths sorted along sample axis => global min/max from each ray's ends.
// min stored as f2ord(min) via atomicMin; max stored as ~f2ord(max) via
// atomicMin, so BOTH words init to 0xFFFFFFFF (single 8-byte memset).
__global__ __launch_bounds__(256) void minmax_ends(const float* __restrict__ z,
                                                   unsigned int* mm) {
    const int ray = blockIdx.x * 256 + threadIdx.x;
    float lmin = z[(size_t)ray * NS];
    float lmax = z[(size_t)ray * NS + (NS - 1)];
#pragma unroll
    for (int off = 32; off > 0; off >>= 1) {
        lmin = fminf(lmin, __shfl_down(lmin, off));
        lmax = fmaxf(lmax, __shfl_down(lmax, off));
    }
    if ((threadIdx.x & 63) == 0) {
        atomicMin(&mm[0], f2ord(lmin));
        atomicMin(&mm[1], ~f2ord(lmax));
    }
}

__global__ __launch_bounds__(TPB) void march_kernel(
    const float* __restrict__ colors, const float* __restrict__ densities,
    const float* __restrict__ depths, const float* __restrict__ semantics,
    const int* __restrict__ levels, const unsigned int* __restrict__ mm,
    float* __restrict__ out) {
    __shared__ float lds[LTOT];
    const int lane = threadIdx.x;
    const int r = lane >> 3;   // local ray 0..7
    const int t = lane & 7;    // owns samples 6t..6t+5 (+ boundary)
    const int ray0 = blockIdx.x * RPT;
    const int ray = ray0 + r;
    const int lv = levels[ray >> 14];
    const float dmin = ord2f(mm[0]);
    const float dmax = ord2f(~mm[1]);

    // ---- colors DMA: 4608B linear (4 full 1KB chunks + one half) ----
    {
        const float* c = colors + (size_t)ray0 * 144;
#pragma unroll
        for (int i = 0; i < 4; ++i)
            __builtin_amdgcn_global_load_lds((as1_cvoid*)(c + i * 256 + lane * 4),
                                             (as3_void*)(lds + LC + i * 256), 16,
                                             0, 0);
        if (lane < 32)
            __builtin_amdgcn_global_load_lds((as1_cvoid*)(c + 1024 + lane * 4),
                                             (as3_void*)(lds + LC + 1024), 16, 0,
                                             0);
    }
    // ---- semantics DMA: one 768B op per ray to padded base 196*rr ----
    // (pad makes the b128 reads below conflict-free: 8 lanes per bank-group)
    if (lane < 48) {
#pragma unroll
        for (int rr = 0; rr < 8; ++rr)
            __builtin_amdgcn_global_load_lds(
                (as1_cvoid*)(semantics + (size_t)(ray0 + rr) * 192 + lane * 4),
                (as3_void*)(lds + LSM + rr * 196), 16, 0, 0);
    }

    // ---- densities/depths straight to registers ----
    const float* dbase = densities + (size_t)ray * 48 + t * 6;
    const float* zbase = depths + (size_t)ray * 48 + t * 6;
    const int dz_t = (t < 7) ? 6 : 0;  // keep last ray's tail load in-bounds
    const float2* dp = (const float2*)dbase;
    float2 g0 = dp[0], g1 = dp[1], g2 = dp[2];
    float g3 = dbase[dz_t];
    const float2* zp = (const float2*)zbase;
    float2 e0 = zp[0], e1 = zp[1], e2 = zp[2];
    float e3 = zbase[dz_t];

    // single drain: DMA-to-LDS completion + the register loads above
    asm volatile("s_waitcnt vmcnt(0)" ::: "memory");

    // ---- LDS -> registers ----
    float C0[7], C1[7], C2[7], DN[7], Z[7], S0[7], S1[7], S2[7], S3[7];
    {
        const float* p0 = lds + LC + r * 144 + 18 * t;
        const float2* p = (const float2*)p0;
        // t==7: q9/qa read neighboring LDS (in-bounds, guarded-unused)
        float2 q0 = p[0], q1 = p[1], q2 = p[2], q3 = p[3], q4 = p[4];
        float2 q5 = p[5], q6 = p[6], q7 = p[7], q8 = p[8], q9 = p[9];
        float qa = p0[20];
        C0[0] = q0.x; C1[0] = q0.y; C2[0] = q1.x;
        C0[1] = q1.y; C1[1] = q2.x; C2[1] = q2.y;
        C0[2] = q3.x; C1[2] = q3.y; C2[2] = q4.x;
        C0[3] = q4.y; C1[3] = q5.x; C2[3] = q5.y;
        C0[4] = q6.x; C1[4] = q6.y; C2[4] = q7.x;
        C0[5] = q7.y; C1[5] = q8.x; C2[5] = q8.y;
        C0[6] = q9.x; C1[6] = q9.y; C2[6] = qa;
    }
    {
        const float4* p = (const float4*)(lds + LSM + r * 196 + 24 * t);
        // t==7: p[6] reads the per-ray pad (uninitialized, guarded-unused)
#pragma unroll
        for (int j = 0; j < 7; ++j) {
            float4 u = p[j];
            S0[j] = u.x; S1[j] = u.y; S2[j] = u.z; S3[j] = u.w;
        }
    }
    DN[0] = g0.x; DN[1] = g0.y; DN[2] = g1.x;
    DN[3] = g1.y; DN[4] = g2.x; DN[5] = g2.y; DN[6] = g3;
    Z[0] = e0.x; Z[1] = e0.y; Z[2] = e1.x;
    Z[3] = e1.y; Z[4] = e2.x; Z[5] = e2.y; Z[6] = e3;

    // ---- local pass: T starts at 1 within this lane's chunk ----
    float T = 1.0f;
    float wl[SPL];
    float acc_r = 0.f, acc_g = 0.f, acc_b = 0.f, acc_d = 0.f;
    float acc_s0 = 0.f, acc_s1 = 0.f, acc_s2 = 0.f, acc_s3 = 0.f;

#pragma unroll
    for (int j = 0; j < SPL; ++j) {
        wl[j] = 0.0f;
        if (j < 5 || t < 7) {  // lane 7 only has 5 segments
            float delta = Z[j + 1] - Z[j];
            float cm0 = (C0[j] + C0[j + 1]) * 0.5f;
            float cm1 = (C1[j] + C1[j + 1]) * 0.5f;
            float cm2 = (C2[j] + C2[j + 1]) * 0.5f;
            float dnm = (DN[j] + DN[j + 1]) * 0.5f;
            float zm = (Z[j] + Z[j + 1]) * 0.5f;
            float sm0 = (S0[j] + S0[j + 1]) * 0.5f;
            float sm1 = (S1[j] + S1[j + 1]) * 0.5f;
            float sm2 = (S2[j] + S2[j + 1]) * 0.5f;
            float sm3 = (S3[j] + S3[j + 1]) * 0.5f;

            float sp_ = softplus_f(dnm);
            float alpha = 1.0f - __expf(-sp_ * delta);

            float factor, o0, o1, o2, o3;
            if (lv == 1) {
                factor = 1.0f - sm0;
                float inv = 1.0f / (sm1 + sm2 + sm3 + EPSF);
                o0 = 0.0f;
                o1 = (sm1 + EPSF) * inv;
                o2 = (sm2 + EPSF) * inv;
                o3 = (sm3 + EPSF) * inv;
            } else if (lv == 2) {
                factor = 1.0f - sm0 - sm3;
                float inv = 1.0f / (sm1 + sm2 + EPSF);
                o0 = 0.0f;
                o1 = (sm1 + EPSF) * inv;
                o2 = (sm2 + EPSF) * inv;
                o3 = 0.0f;
            } else {
                factor = 1.0f;
                o0 = sm0; o1 = sm1; o2 = sm2; o3 = sm3;
            }

            alpha *= factor;
            float w = alpha * T;
            T *= (1.0f - alpha + 1e-10f);
            wl[j] = w;

            acc_r += w * cm0;
            acc_g += w * cm1;
            acc_b += w * cm2;
            acc_d += w * zm;
            acc_s0 += w * o0;
            acc_s1 += w * o1;
            acc_s2 += w * o2;
            acc_s3 += w * o3;
        }
    }

    // ---- inclusive product scan of local transmittance across 8 lanes ----
    float p = T;
#pragma unroll
    for (int off = 1; off < KL; off <<= 1) {
        float u = __shfl_up(p, off, KL);
        if (t >= off) p *= u;
    }
    float Tstart = __shfl_up(p, 1, KL);
    if (t == 0) Tstart = 1.0f;

    acc_r *= Tstart; acc_g *= Tstart; acc_b *= Tstart; acc_d *= Tstart;
    acc_s0 *= Tstart; acc_s1 *= Tstart; acc_s2 *= Tstart; acc_s3 *= Tstart;

    // ---- weights into consumed colors region (linear image of global) ----
#pragma unroll
    for (int j = 0; j < SPL; ++j) {
        if (j < 5 || t < 7)
            lds[LW + r * NSEG + t * SPL + j] = wl[j] * Tstart;
    }

    // ---- per-lane partials into consumed semantics region ----
    {
        const int pb = LP + r * 72 + t * 9;
        lds[pb + 0] = acc_r;  lds[pb + 1] = acc_g;
        lds[pb + 2] = acc_b;  lds[pb + 3] = acc_d;
        lds[pb + 4] = acc_s0; lds[pb + 5] = acc_s1;
        lds[pb + 6] = acc_s2; lds[pb + 7] = acc_s3;
    }

    // ---- coalesced float4 write-out of the tile's 376 weight floats ----
    {
        const float4* src = (const float4*)(lds + LW);
        float4* dst = (float4*)(out + (size_t)NRAYS * 8 + (size_t)ray0 * NSEG);
        dst[lane] = src[lane];
        if (lane < 30) dst[64 + lane] = src[64 + lane];
    }

    // ---- transposed re-read: lane <-> (ray rr, quantity qq) ----
    {
        const int rr = lane >> 3, qq = lane & 7;
        const int qb = LP + rr * 72 + qq;
        float v = lds[qb] + lds[qb + 9];
        v += lds[qb + 18]; v += lds[qb + 27];
        v += lds[qb + 36]; v += lds[qb + 45];
        v += lds[qb + 54]; v += lds[qb + 63];

        const int oray = ray0 + rr;
        size_t oidx;
        if (qq < 3) {
            oidx = (size_t)oray * 3 + qq;
        } else if (qq == 3) {
            if (isnan(v)) v = INFINITY;
            v = fminf(fmaxf(v, dmin), dmax);
            oidx = (size_t)NRAYS * 3 + oray;
        } else {
            oidx = (size_t)NRAYS * 4 + (size_t)oray * 4 + (qq - 4);
        }
        out[oidx] = v;
    }
}

extern "C" void kernel_launch(void* const* d_in, const int* in_sizes, int n_in,
                              void* d_out, int out_size, void* d_ws, size_t ws_size,
                              hipStream_t stream) {
    const float* colors = (const float*)d_in[0];
    const float* densities = (const float*)d_in[1];
    const float* depths = (const float*)d_in[2];
    const float* semantics = (const float*)d_in[3];
    const int* levels = (const int*)d_in[4];
    float* out = (float*)d_out;
    unsigned int* mm = (unsigned int*)d_ws;

    hipMemsetAsync(mm, 0xFF, 8, stream);  // init both ordinals to UINT_MAX
    minmax_ends<<<NRAYS / 256, 256, 0, stream>>>(depths, mm);
    march_kernel<<<NBLK, TPB, 0, stream>>>(colors, densities, depths, semantics,
                                           levels, mm, out);
}

// Round 7
// 30.097 us; speedup vs baseline: 1.9921x; 1.8731x over previous
//
#include <hip/hip_runtime.h>
#include <math.h>

#define EPSF 1e-6f
#define NB 4
#define NR 16384
#define NS 48
#define NSEG 47
#define NRAYS (NB * NR)
#define KL 8                 // lanes per ray
#define SPL 6                // samples per lane
#define RPT 8                // rays per tile == rays per wave == rays per block
#define TPB 64               // single-wave blocks: no s_barrier anywhere
#define NBLK (NRAYS / RPT)   // 8192 blocks

// LDS dword offsets (13984 B total -> 11 blocks/CU)
#define LC 0                 // colors, linear image: 8*144 = 1152
#define LSM 1152             // semantics, PADDED per-ray stride 196: 8*196 = 1568
#define LD 2720              // densities, linear image: 8*48 = 384
#define LZ 3104              // depths, linear image: 8*48 = 384
#define LTOT 3496            // + small pad
#define LW LC                // weights staging reuses colors region (376 dwords)
#define LP LSM               // partials reuse semantics region (576 dwords)

typedef const __attribute__((address_space(1))) void as1_cvoid;
typedef __attribute__((address_space(3))) void as3_void;

// fast softplus: max(x,0) + log(1+exp(-|x|)) with native exp/log
__device__ __forceinline__ float softplus_f(float x) {
    return fmaxf(x, 0.0f) + __logf(1.0f + __expf(-fabsf(x)));
}

__global__ __launch_bounds__(TPB) void march_kernel(
    const float* __restrict__ colors, const float* __restrict__ densities,
    const float* __restrict__ depths, const float* __restrict__ semantics,
    const int* __restrict__ levels, float2* __restrict__ ws2,
    float* __restrict__ out) {
    __shared__ float lds[LTOT];
    const int lane = threadIdx.x;
    const int r = lane >> 3;   // local ray 0..7
    const int t = lane & 7;    // owns samples 6t..6t+5 (+ boundary)
    const int ray0 = blockIdx.x * RPT;
    const int ray = ray0 + r;
    const int lv = levels[ray >> 14];

    // ---- ALL inputs via coalesced global->LDS DMA (17 vmem ops, 0 VGPR) ----
    {   // colors: 4608B linear (4 full 1KB chunks + one half)
        const float* c = colors + (size_t)ray0 * 144;
#pragma unroll
        for (int i = 0; i < 4; ++i)
            __builtin_amdgcn_global_load_lds((as1_cvoid*)(c + i * 256 + lane * 4),
                                             (as3_void*)(lds + LC + i * 256), 16,
                                             0, 0);
        if (lane < 32)
            __builtin_amdgcn_global_load_lds((as1_cvoid*)(c + 1024 + lane * 4),
                                             (as3_void*)(lds + LC + 1024), 16, 0,
                                             0);
    }
    // semantics: one 768B op per ray to padded base 196*rr (pad -> the b128
    // reads below are conflict-free: 8 lanes per bank-group)
    if (lane < 48) {
#pragma unroll
        for (int rr = 0; rr < 8; ++rr)
            __builtin_amdgcn_global_load_lds(
                (as1_cvoid*)(semantics + (size_t)(ray0 + rr) * 192 + lane * 4),
                (as3_void*)(lds + LSM + rr * 196), 16, 0, 0);
    }
    {   // densities + depths: 1536B linear each (1 full chunk + one half)
        const float* d = densities + (size_t)ray0 * 48;
        const float* z = depths + (size_t)ray0 * 48;
        __builtin_amdgcn_global_load_lds((as1_cvoid*)(d + lane * 4),
                                         (as3_void*)(lds + LD), 16, 0, 0);
        __builtin_amdgcn_global_load_lds((as1_cvoid*)(z + lane * 4),
                                         (as3_void*)(lds + LZ), 16, 0, 0);
        if (lane < 32) {
            __builtin_amdgcn_global_load_lds((as1_cvoid*)(d + 256 + lane * 4),
                                             (as3_void*)(lds + LD + 256), 16, 0,
                                             0);
            __builtin_amdgcn_global_load_lds((as1_cvoid*)(z + 256 + lane * 4),
                                             (as3_void*)(lds + LZ + 256), 16, 0,
                                             0);
        }
    }

    // single drain of the DMA queue (only vmem ops issued so far)
    asm volatile("s_waitcnt vmcnt(0)" ::: "memory");

    // ---- per-block depth extrema -> ws (depths sorted per ray) ----
    {
        const int rr = lane & 7;
        float a = lds[LZ + rr * 48];        // ray rr, sample 0
        float b = lds[LZ + rr * 48 + 47];   // ray rr, sample 47
#pragma unroll
        for (int k = 1; k < 8; k <<= 1) {
            a = fminf(a, __shfl_xor(a, k));
            b = fmaxf(b, __shfl_xor(b, k));
        }
        if (lane == 0) ws2[blockIdx.x] = make_float2(a, b);
    }

    // ---- LDS -> registers ----
    float C0[7], C1[7], C2[7], DN[7], Z[7], S0[7], S1[7], S2[7], S3[7];
    {
        const float* p0 = lds + LC + r * 144 + 18 * t;
        const float2* p = (const float2*)p0;
        // t==7: q9/qa read neighboring LDS (in-bounds, guarded-unused)
        float2 q0 = p[0], q1 = p[1], q2 = p[2], q3 = p[3], q4 = p[4];
        float2 q5 = p[5], q6 = p[6], q7 = p[7], q8 = p[8], q9 = p[9];
        float qa = p0[20];
        C0[0] = q0.x; C1[0] = q0.y; C2[0] = q1.x;
        C0[1] = q1.y; C1[1] = q2.x; C2[1] = q2.y;
        C0[2] = q3.x; C1[2] = q3.y; C2[2] = q4.x;
        C0[3] = q4.y; C1[3] = q5.x; C2[3] = q5.y;
        C0[4] = q6.x; C1[4] = q6.y; C2[4] = q7.x;
        C0[5] = q7.y; C1[5] = q8.x; C2[5] = q8.y;
        C0[6] = q9.x; C1[6] = q9.y; C2[6] = qa;
    }
    {
        const float4* p = (const float4*)(lds + LSM + r * 196 + 24 * t);
        // t==7: p[6] reads the per-ray pad (uninitialized, guarded-unused)
#pragma unroll
        for (int j = 0; j < 7; ++j) {
            float4 u = p[j];
            S0[j] = u.x; S1[j] = u.y; S2[j] = u.z; S3[j] = u.w;
        }
    }
    {
        const int dsel = (t < 7) ? 6 : 0;  // t==7 boundary guarded-unused
        const int bd = LD + r * 48 + 6 * t;
        const float2* p = (const float2*)(lds + bd);
        float2 a0 = p[0], a1 = p[1], a2 = p[2];
        DN[0] = a0.x; DN[1] = a0.y; DN[2] = a1.x;
        DN[3] = a1.y; DN[4] = a2.x; DN[5] = a2.y;
        DN[6] = lds[bd + dsel];
        const int bz = LZ + r * 48 + 6 * t;
        const float2* q = (const float2*)(lds + bz);
        float2 b0 = q[0], b1 = q[1], b2 = q[2];
        Z[0] = b0.x; Z[1] = b0.y; Z[2] = b1.x;
        Z[3] = b1.y; Z[4] = b2.x; Z[5] = b2.y;
        Z[6] = lds[bz + dsel];
    }

    // ---- local pass: T starts at 1 within this lane's chunk ----
    float T = 1.0f;
    float wl[SPL];
    float acc_r = 0.f, acc_g = 0.f, acc_b = 0.f, acc_d = 0.f;
    float acc_s0 = 0.f, acc_s1 = 0.f, acc_s2 = 0.f, acc_s3 = 0.f;

#pragma unroll
    for (int j = 0; j < SPL; ++j) {
        wl[j] = 0.0f;
        if (j < 5 || t < 7) {  // lane 7 only has 5 segments
            float delta = Z[j + 1] - Z[j];
            float cm0 = (C0[j] + C0[j + 1]) * 0.5f;
            float cm1 = (C1[j] + C1[j + 1]) * 0.5f;
            float cm2 = (C2[j] + C2[j + 1]) * 0.5f;
            float dnm = (DN[j] + DN[j + 1]) * 0.5f;
            float zm = (Z[j] + Z[j + 1]) * 0.5f;
            float sm0 = (S0[j] + S0[j + 1]) * 0.5f;
            float sm1 = (S1[j] + S1[j + 1]) * 0.5f;
            float sm2 = (S2[j] + S2[j + 1]) * 0.5f;
            float sm3 = (S3[j] + S3[j + 1]) * 0.5f;

            float sp_ = softplus_f(dnm);
            float alpha = 1.0f - __expf(-sp_ * delta);

            float factor, o0, o1, o2, o3;
            if (lv == 1) {
                factor = 1.0f - sm0;
                float inv = 1.0f / (sm1 + sm2 + sm3 + EPSF);
                o0 = 0.0f;
                o1 = (sm1 + EPSF) * inv;
                o2 = (sm2 + EPSF) * inv;
                o3 = (sm3 + EPSF) * inv;
            } else if (lv == 2) {
                factor = 1.0f - sm0 - sm3;
                float inv = 1.0f / (sm1 + sm2 + EPSF);
                o0 = 0.0f;
                o1 = (sm1 + EPSF) * inv;
                o2 = (sm2 + EPSF) * inv;
                o3 = 0.0f;
            } else {
                factor = 1.0f;
                o0 = sm0; o1 = sm1; o2 = sm2; o3 = sm3;
            }

            alpha *= factor;
            float w = alpha * T;
            T *= (1.0f - alpha + 1e-10f);
            wl[j] = w;

            acc_r += w * cm0;
            acc_g += w * cm1;
            acc_b += w * cm2;
            acc_d += w * zm;
            acc_s0 += w * o0;
            acc_s1 += w * o1;
            acc_s2 += w * o2;
            acc_s3 += w * o3;
        }
    }

    // ---- inclusive product scan of local transmittance across 8 lanes ----
    float p = T;
#pragma unroll
    for (int off = 1; off < KL; off <<= 1) {
        float u = __shfl_up(p, off, KL);
        if (t >= off) p *= u;
    }
    float Tstart = __shfl_up(p, 1, KL);
    if (t == 0) Tstart = 1.0f;

    acc_r *= Tstart; acc_g *= Tstart; acc_b *= Tstart; acc_d *= Tstart;
    acc_s0 *= Tstart; acc_s1 *= Tstart; acc_s2 *= Tstart; acc_s3 *= Tstart;

    // ---- weights into consumed colors region (linear image of global) ----
#pragma unroll
    for (int j = 0; j < SPL; ++j) {
        if (j < 5 || t < 7)
            lds[LW + r * NSEG + t * SPL + j] = wl[j] * Tstart;
    }

    // ---- per-lane partials into consumed semantics region ----
    {
        const int pb = LP + r * 72 + t * 9;
        lds[pb + 0] = acc_r;  lds[pb + 1] = acc_g;
        lds[pb + 2] = acc_b;  lds[pb + 3] = acc_d;
        lds[pb + 4] = acc_s0; lds[pb + 5] = acc_s1;
        lds[pb + 6] = acc_s2; lds[pb + 7] = acc_s3;
    }

    // ---- coalesced float4 write-out of the tile's 376 weight floats ----
    {
        const float4* src = (const float4*)(lds + LW);
        float4* dst = (float4*)(out + (size_t)NRAYS * 8 + (size_t)ray0 * NSEG);
        dst[lane] = src[lane];
        if (lane < 30) dst[64 + lane] = src[64 + lane];
    }

    // ---- transposed re-read: lane <-> (ray rr, quantity qq) ----
    {
        const int rr = lane >> 3, qq = lane & 7;
        const int qb = LP + rr * 72 + qq;
        float v = lds[qb] + lds[qb + 9];
        v += lds[qb + 18]; v += lds[qb + 27];
        v += lds[qb + 36]; v += lds[qb + 45];
        v += lds[qb + 54]; v += lds[qb + 63];

        const int oray = ray0 + rr;
        size_t oidx;
        if (qq < 3) {
            oidx = (size_t)oray * 3 + qq;
        } else if (qq == 3) {
            if (isnan(v)) v = INFINITY;  // clip happens in clip_depth
            oidx = (size_t)NRAYS * 3 + oray;
        } else {
            oidx = (size_t)NRAYS * 4 + (size_t)oray * 4 + (qq - 4);
        }
        out[oidx] = v;
    }
}

// reduce the 8192 per-block (min,max) pairs, then clip 1024 contiguous
// depth values per block with one float4 RMW per thread.
__global__ __launch_bounds__(256) void clip_depth(const float2* __restrict__ ws2,
                                                  float* __restrict__ dout) {
    __shared__ float smn[4], smx[4];
    float mn = INFINITY, mx = -INFINITY;
#pragma unroll
    for (int k = 0; k < 32; ++k) {  // 8192 pairs / 256 threads
        float2 v = ws2[threadIdx.x + (k << 8)];
        mn = fminf(mn, v.x);
        mx = fmaxf(mx, v.y);
    }
#pragma unroll
    for (int off = 32; off > 0; off >>= 1) {
        mn = fminf(mn, __shfl_down(mn, off));
        mx = fmaxf(mx, __shfl_down(mx, off));
    }
    if ((threadIdx.x & 63) == 0) {
        smn[threadIdx.x >> 6] = mn;
        smx[threadIdx.x >> 6] = mx;
    }
    __syncthreads();
    mn = fminf(fminf(smn[0], smn[1]), fminf(smn[2], smn[3]));
    mx = fmaxf(fmaxf(smx[0], smx[1]), fmaxf(smx[2], smx[3]));

    float4* d4 = (float4*)dout;
    const int i = blockIdx.x * 256 + threadIdx.x;  // 64 blocks * 256 = 16384
    float4 v = d4[i];
    v.x = fminf(fmaxf(v.x, mn), mx);
    v.y = fminf(fmaxf(v.y, mn), mx);
    v.z = fminf(fmaxf(v.z, mn), mx);
    v.w = fminf(fmaxf(v.w, mn), mx);
    d4[i] = v;
}

extern "C" void kernel_launch(void* const* d_in, const int* in_sizes, int n_in,
                              void* d_out, int out_size, void* d_ws, size_t ws_size,
                              hipStream_t stream) {
    const float* colors = (const float*)d_in[0];
    const float* densities = (const float*)d_in[1];
    const float* depths = (const float*)d_in[2];
    const float* semantics = (const float*)d_in[3];
    const int* levels = (const int*)d_in[4];
    float* out = (float*)d_out;
    float2* ws2 = (float2*)d_ws;  // 8192 float2 = 64 KB

    march_kernel<<<NBLK, TPB, 0, stream>>>(colors, densities, depths, semantics,
                                           levels, ws2, out);
    clip_depth<<<64, 256, 0, stream>>>(ws2, out + (size_t)NRAYS * 3);
}